// Round 2
// baseline (354.353 us; speedup 1.0000x reference)
//
#include <hip/hip_runtime.h>

#define BN 2048   // batch
#define TN 2048   // time
#define SLOT 24   // floats per (b,chunk) result slot (16 P + 4 off + 1 gold + 3 pad)

__device__ __forceinline__ float ex2(float x){ return __builtin_amdgcn_exp2f(x); }
__device__ __forceinline__ float lg2(float x){ return __builtin_amdgcn_logf(x); }
__device__ __forceinline__ float rcpf(float x){ return __builtin_amdgcn_rcpf(x); }

constexpr float kLog2e = 1.4426950408889634f;
constexpr float kLn2   = 0.6931471805599453f;

__device__ __forceinline__ float fast_tanh(float x){
    float ax = fabsf(x);
    float e  = ex2(ax * (-2.0f * kLog2e));     // exp(-2|x|)
    float t  = (1.0f - e) * rcpf(1.0f + e);
    return copysignf(t, x);
}

__device__ __forceinline__ float sel4(float v0, float v1, float v2, float v3, int idx){
    float r = (idx == 1) ? v1 : v0;
    r = (idx == 2) ? v2 : r;
    r = (idx == 3) ? v3 : r;
    return r;
}

// async global->LDS, 16B per lane, dest = wave-uniform base + lane*16
__device__ __forceinline__ void gload_lds16(const void* g, void* l) {
    __builtin_amdgcn_global_load_lds(
        (const __attribute__((address_space(1))) void*)g,
        (__attribute__((address_space(3))) void*)l, 16, 0, 0);
}

struct P1Params {
    float AL[4][4], M[4][4];
    float wsv[4], wwv[4], wnv[4];
    float bwc, bnc;
    const float* sA; const float* sM;
    float tc4[4];
};

// one generic CRF step (exp-space, NCOL alpha columns)
template <int NCOL>
__device__ __forceinline__ void step_generic(
    const P1Params& pp, float fi0, float fi1, float fi2, float fi3,
    float bv, int tg, bool renorm,
    float (&P)[4][NCOL], float (&lacc)[NCOL], float& gold, int& prev)
{
    const bool hw = bv > 0.5f;
    const float bc = hw ? pp.bwc : pp.bnc;
    float g[4], gL[4];
    #pragma unroll
    for (int j = 0; j < 4; ++j) {
        float x = fmaf(bv, pp.wsv[j], bc);
        g[j]  = (hw ? pp.wwv[j] : pp.wnv[j]) * fast_tanh(x);
        gL[j] = g[j] * kLog2e;
    }
    const float fiL[4] = { fi0 * kLog2e, fi1 * kLog2e, fi2 * kLog2e, fi3 * kLog2e };
    float nP[4][NCOL];
    #pragma unroll
    for (int i = 0; i < 4; ++i)
        #pragma unroll
        for (int j = 0; j < NCOL; ++j) nP[i][j] = 0.0f;
    #pragma unroll
    for (int k = 0; k < 4; ++k) {
        float Ek[4];
        #pragma unroll
        for (int i = 0; i < 4; ++i)
            Ek[i] = ex2(fmaf(gL[k], pp.M[i][k], fiL[i] + pp.AL[i][k]));
        #pragma unroll
        for (int j = 0; j < NCOL; ++j) {
            const float pk = P[k][j];
            #pragma unroll
            for (int i = 0; i < 4; ++i) nP[i][j] = fmaf(Ek[i], pk, nP[i][j]);
        }
    }
    #pragma unroll
    for (int i = 0; i < 4; ++i)
        #pragma unroll
        for (int j = 0; j < NCOL; ++j) P[i][j] = nP[i][j];

    const int idx = tg * 4 + prev;
    gold += pp.sA[idx] + sel4(g[0], g[1], g[2], g[3], prev) * pp.sM[idx]
          + sel4(fi0, fi1, fi2, fi3, tg);
    prev = tg;

    if (renorm) {     // exact pow2 renorm
        #pragma unroll
        for (int j = 0; j < NCOL; ++j) {
            float m = fmaxf(fmaxf(P[0][j], P[1][j]), fmaxf(P[2][j], P[3][j]));
            int ee = (int)((__float_as_uint(m) >> 23) & 255u) - 126;
            float sc = __uint_as_float((unsigned)(127 - ee) << 23);
            lacc[j] += (float)ee;
            #pragma unroll
            for (int i = 0; i < 4; ++i) P[i][j] *= sc;
        }
    }
}

// 8 steps of one chunk, feats read from wave-private LDS (stride-13 float4/chunk)
template <int NCOL, bool C0>
__device__ __forceinline__ void trip8(
    const float4* myF, const float (&Bv)[8], const int (&Tg)[8],
    const P1Params& pp,
    float (&P)[4][NCOL], float (&lacc)[NCOL], float& gold, int& prev)
{
    #pragma unroll
    for (int p = 0; p < 4; ++p) {
        const float4 fA = myF[3*p], fB = myF[3*p+1], fC = myF[3*p+2];
        {   // step s = 2p : floats 12p+0..3 = fA.xyzw
            const float fi0 = fA.x, fi1 = fA.y, fi2 = fA.z, fi3 = fA.w;
            if (C0 && p == 0) {
                // closed-form t=0: alpha1[i] = f[0,i] + trans[i,START]
                const float a0 = fi0 + pp.tc4[0], a1 = fi1 + pp.tc4[1];
                const float a2 = fi2 + pp.tc4[2], a3 = fi3 + pp.tc4[3];
                const float mx = fmaxf(fmaxf(a0, a1), fmaxf(a2, a3));
                P[0][0] = ex2((a0 - mx) * kLog2e);
                P[1][0] = ex2((a1 - mx) * kLog2e);
                P[2][0] = ex2((a2 - mx) * kLog2e);
                P[3][0] = ex2((a3 - mx) * kLog2e);
                lacc[0] = mx * kLog2e;
                const int tg0 = Tg[0];
                gold = sel4(pp.tc4[0], pp.tc4[1], pp.tc4[2], pp.tc4[3], tg0)
                     + sel4(fi0, fi1, fi2, fi3, tg0);
                prev = tg0;
            } else {
                step_generic<NCOL>(pp, fi0, fi1, fi2, fi3, Bv[2*p], Tg[2*p],
                                   ((2*p) & 3) == 3, P, lacc, gold, prev);
            }
        }
        {   // step s = 2p+1 : floats 12p+6..9 = fB.zw, fC.xy
            const float fi0 = fB.z, fi1 = fB.w, fi2 = fC.x, fi3 = fC.y;
            step_generic<NCOL>(pp, fi0, fi1, fi2, fi3, Bv[2*p+1], Tg[2*p+1],
                               ((2*p+1) & 3) == 3, P, lacc, gold, prev);
        }
    }
}

// ============ CC=256 primary path: 1 block = 1 batch, 4 waves x 64 chunks ============
__global__ void __launch_bounds__(256, 3)
crf_phase1_t(const float* __restrict__ feats, const float* __restrict__ bias,
             const int* __restrict__ tags, const float* __restrict__ trans,
             const float* __restrict__ wsh, const float* __restrict__ bno,
             const float* __restrict__ bwi, const float* __restrict__ wwo,
             const float* __restrict__ wno, const float* __restrict__ mult,
             float* __restrict__ matAll)
{
    constexpr int CC = 256, TCH = 8;
    const int w = threadIdx.x >> 6;     // wave 0..3
    const int L = threadIdx.x & 63;     // lane
    const int b = blockIdx.x;
    const int c = threadIdx.x;          // chunk id 0..255

    // wave-private staging: 64 chunks x 13 float4 (12 used + 1 pad; gcd(13,8)=1
    // => conflict-free ds_read_b128 and near-floor gload_lds writes)
    __shared__ float4 ldsA[4][13 * 64];           // 53248 B
    __shared__ float sA[16], sM[16];
    float4* ldsW = ldsA[w];

    // ---- stage feats: 13 global_load_lds dwordx4, pre-swizzled source ----
    {
        const float4* gwin4 = (const float4*)(feats + ((size_t)b * TN + (size_t)w * 64 * TCH) * 6);
        #pragma unroll
        for (int q = 0; q < 13; ++q) {
            const int S  = q * 64 + L;            // linear LDS float4 slot
            const int cS = (S * 2521) >> 15;      // S/13 (exact for S<832)
            int j = S - cS * 13;
            j = (j > 11) ? 11 : j;                // pad slot -> duplicate (never read)
            gload_lds16(gwin4 + cS * 12 + j, &ldsW[q * 64]);
        }
    }

    // ---- per-lane direct loads (bias/tags, 32B/lane) ----
    float Bv[8]; int Tg[8];
    {
        const int tbase = c * TCH;
        const float4* bp = (const float4*)(bias + (size_t)b * TN + tbase);
        const float4 b0 = bp[0], b1 = bp[1];
        Bv[0]=b0.x; Bv[1]=b0.y; Bv[2]=b0.z; Bv[3]=b0.w;
        Bv[4]=b1.x; Bv[5]=b1.y; Bv[6]=b1.z; Bv[7]=b1.w;
        const int4* tp = (const int4*)(tags + (size_t)b * TN + tbase);
        const int4 t0 = tp[0], t1 = tp[1];
        Tg[0]=t0.x; Tg[1]=t0.y; Tg[2]=t0.z; Tg[3]=t0.w;
        Tg[4]=t1.x; Tg[5]=t1.y; Tg[6]=t1.z; Tg[7]=t1.w;
    }
    int prev = 0;
    if (c != 0) prev = tags[(size_t)b * TN + c * TCH - 1];

    if (threadIdx.x < 16) {
        const int i = threadIdx.x >> 2, j = threadIdx.x & 3;
        sA[threadIdx.x] = trans[i * 6 + j];
        const float m0 = mult[j], m1 = mult[4 + j], m2 = mult[8 + j], m3 = mult[12 + j];
        const float mx = fmaxf(fmaxf(m0, m1), fmaxf(m2, m3));
        const float e0 = ex2((m0 - mx) * kLog2e), e1 = ex2((m1 - mx) * kLog2e);
        const float e2 = ex2((m2 - mx) * kLog2e), e3 = ex2((m3 - mx) * kLog2e);
        const float inv = rcpf(e0 + e1 + e2 + e3);
        const float ei = (i == 0) ? e0 : (i == 1) ? e1 : (i == 2) ? e2 : e3;
        sM[threadIdx.x] = (i == j) ? -1.0f : ei * inv;
    }
    __syncthreads();
    asm volatile("s_waitcnt vmcnt(0)" ::: "memory");

    P1Params pp;
    #pragma unroll
    for (int i = 0; i < 4; ++i)
        #pragma unroll
        for (int j = 0; j < 4; ++j) {
            pp.AL[i][j] = trans[i * 6 + j] * kLog2e;
            pp.M[i][j]  = sM[i * 4 + j];
        }
    #pragma unroll
    for (int j = 0; j < 4; ++j) { pp.wsv[j] = wsh[j]; pp.wwv[j] = wwo[j]; pp.wnv[j] = wno[j]; }
    pp.bwc = bwi[0]; pp.bnc = bno[0];
    pp.sA = sA; pp.sM = sM;
    pp.tc4[0] = trans[4]; pp.tc4[1] = trans[10]; pp.tc4[2] = trans[16]; pp.tc4[3] = trans[22];

    const float4* myF = &ldsW[L * 13];

    float o[SLOT];
    float gold = 0.0f;
    if (c == 0) {
        float P[4][1], lacc[1];
        trip8<1, true>(myF, Bv, Tg, pp, P, lacc, gold, prev);
        #pragma unroll
        for (int i = 0; i < 4; ++i)
            #pragma unroll
            for (int j = 0; j < 4; ++j) o[i * 4 + j] = P[i][0];   // rank-1 lift
        #pragma unroll
        for (int j = 0; j < 4; ++j) o[16 + j] = lacc[0];
    } else {
        float P[4][4], lacc[4] = {0.f, 0.f, 0.f, 0.f};
        #pragma unroll
        for (int i = 0; i < 4; ++i)
            #pragma unroll
            for (int j = 0; j < 4; ++j) P[i][j] = (i == j) ? 1.0f : 0.0f;
        trip8<4, false>(myF, Bv, Tg, pp, P, lacc, gold, prev);
        #pragma unroll
        for (int i = 0; i < 4; ++i)
            #pragma unroll
            for (int j = 0; j < 4; ++j) o[i * 4 + j] = P[i][j];
        #pragma unroll
        for (int j = 0; j < 4; ++j) o[16 + j] = lacc[j];
    }
    o[20] = gold; o[21] = 0.f; o[22] = 0.f; o[23] = 0.f;

    // transposed store: matAll[b][q][c] -> lane-consecutive float4 per q
    float4* mp = (float4*)matAll + (size_t)b * 6 * CC;
    #pragma unroll
    for (int q = 0; q < 6; ++q)
        mp[q * CC + c] = make_float4(o[4*q], o[4*q+1], o[4*q+2], o[4*q+3]);
}

// C = A∘B (A later, B earlier) in exp-space with per-column base-2 offsets.
__device__ __forceinline__ void compose4(
    const float (&Ae)[4][4], const float (&sa)[4],
    const float (&Be)[4][4], const float (&sb)[4],
    float (&Ce)[4][4], float (&sc)[4])
{
    const float maxA = fmaxf(fmaxf(sa[0], sa[1]), fmaxf(sa[2], sa[3]));
    float Ap[4][4];
    #pragma unroll
    for (int k = 0; k < 4; ++k) {
        const float wk = ex2(sa[k] - maxA);
        #pragma unroll
        for (int i = 0; i < 4; ++i) Ap[i][k] = Ae[i][k] * wk;
    }
    #pragma unroll
    for (int j = 0; j < 4; ++j) {
        float c0 = 0.f, c1 = 0.f, c2 = 0.f, c3 = 0.f;
        #pragma unroll
        for (int k = 0; k < 4; ++k) {
            const float bk = Be[k][j];
            c0 = fmaf(Ap[0][k], bk, c0);
            c1 = fmaf(Ap[1][k], bk, c1);
            c2 = fmaf(Ap[2][k], bk, c2);
            c3 = fmaf(Ap[3][k], bk, c3);
        }
        const float m = fmaxf(fmaxf(c0, c1), fmaxf(c2, c3));
        const int ee = (int)((__float_as_uint(m) >> 23) & 255u) - 126;
        const float scf = __uint_as_float((unsigned)(127 - ee) << 23);
        Ce[0][j] = c0 * scf; Ce[1][j] = c1 * scf;
        Ce[2][j] = c2 * scf; Ce[3][j] = c3 * scf;
        sc[j] = sb[j] + maxA + (float)ee;
    }
}

// CC=256 phase2: 1 block = 1 batch, thread = chunk, coalesced transposed loads
__global__ void __launch_bounds__(256)
crf_phase2_t(const float* __restrict__ matAll, const float* __restrict__ trans,
             const int* __restrict__ tags, float* __restrict__ out)
{
    constexpr int CC = 256;
    const int b = blockIdx.x;
    const int c = threadIdx.x;
    const int L = c & 63, w = c >> 6;

    const float4* mp = (const float4*)matAll + (size_t)b * 6 * CC;
    float4 v[6];
    #pragma unroll
    for (int q = 0; q < 6; ++q) v[q] = mp[q * CC + c];

    float Pe[4][4], so[4], gold;
    #pragma unroll
    for (int i = 0; i < 4; ++i) {
        Pe[i][0] = (&v[i].x)[0]; Pe[i][1] = (&v[i].x)[1];
        Pe[i][2] = (&v[i].x)[2]; Pe[i][3] = (&v[i].x)[3];
    }
    so[0] = v[4].x; so[1] = v[4].y; so[2] = v[4].z; so[3] = v[4].w;
    gold = v[5].x;

    // in-wave ordered tree over 64 chunks
    #pragma unroll
    for (int d = 1; d < 64; d <<= 1) {
        float oP[4][4], os[4];
        #pragma unroll
        for (int i = 0; i < 4; ++i)
            #pragma unroll
            for (int j = 0; j < 4; ++j) oP[i][j] = __shfl_xor(Pe[i][j], d, 64);
        #pragma unroll
        for (int j = 0; j < 4; ++j) os[j] = __shfl_xor(so[j], d, 64);
        const bool hi = (L & d) != 0;
        float Ae[4][4], Be[4][4], sa[4], sb[4];
        #pragma unroll
        for (int i = 0; i < 4; ++i)
            #pragma unroll
            for (int j = 0; j < 4; ++j) {
                Ae[i][j] = hi ? Pe[i][j] : oP[i][j];
                Be[i][j] = hi ? oP[i][j] : Pe[i][j];
            }
        #pragma unroll
        for (int j = 0; j < 4; ++j) {
            sa[j] = hi ? so[j] : os[j];
            sb[j] = hi ? os[j] : so[j];
        }
        float Ce[4][4], sc[4];
        compose4(Ae, sa, Be, sb, Ce, sc);
        #pragma unroll
        for (int i = 0; i < 4; ++i)
            #pragma unroll
            for (int j = 0; j < 4; ++j) Pe[i][j] = Ce[i][j];
        #pragma unroll
        for (int j = 0; j < 4; ++j) so[j] = sc[j];
    }
    #pragma unroll
    for (int d = 1; d < 64; d <<= 1) gold += __shfl_xor(gold, d, 64);

    // cross-wave (4 wave-products, later ∘ earlier), serial on thread 0
    __shared__ float red[4][24];
    if (L == 0) {
        #pragma unroll
        for (int i = 0; i < 4; ++i)
            #pragma unroll
            for (int j = 0; j < 4; ++j) red[w][i * 4 + j] = Pe[i][j];
        #pragma unroll
        for (int j = 0; j < 4; ++j) red[w][16 + j] = so[j];
        red[w][20] = gold;
    }
    __syncthreads();
    if (threadIdx.x == 0) {
        float Pt[4][4], st[4];
        #pragma unroll
        for (int i = 0; i < 4; ++i)
            #pragma unroll
            for (int j = 0; j < 4; ++j) Pt[i][j] = red[0][i * 4 + j];
        #pragma unroll
        for (int j = 0; j < 4; ++j) st[j] = red[0][16 + j];
        float gsum = red[0][20] + red[1][20] + red[2][20] + red[3][20];
        #pragma unroll
        for (int ww = 1; ww < 4; ++ww) {
            float Ae[4][4], sa[4], Ce[4][4], scv[4];
            #pragma unroll
            for (int i = 0; i < 4; ++i)
                #pragma unroll
                for (int j = 0; j < 4; ++j) Ae[i][j] = red[ww][i * 4 + j];
            #pragma unroll
            for (int j = 0; j < 4; ++j) sa[j] = red[ww][16 + j];
            compose4(Ae, sa, Pt, st, Ce, scv);
            #pragma unroll
            for (int i = 0; i < 4; ++i)
                #pragma unroll
                for (int j = 0; j < 4; ++j) Pt[i][j] = Ce[i][j];
            #pragma unroll
            for (int j = 0; j < 4; ++j) st[j] = scv[j];
        }
        const float t50 = trans[30], t51 = trans[31], t52 = trans[32], t53 = trans[33];
        const float ssum = Pt[0][0] * ex2(t50 * kLog2e) + Pt[1][0] * ex2(t51 * kLog2e)
                         + Pt[2][0] * ex2(t52 * kLog2e) + Pt[3][0] * ex2(t53 * kLog2e);
        const float fwd = (st[0] + lg2(ssum)) * kLn2;
        const int lastT = tags[(size_t)b * TN + TN - 1];
        const float gfin = gsum + sel4(t50, t51, t52, t53, lastT);
        out[b] = fwd - gfin;
    }
}

// ==================== fallback (round-1 kernels, small workspace) ====================
template <int NCOL, bool CHUNK0, int TCH>
__device__ __forceinline__ void run_chunk_fb(
    int b, int c,
    const float* __restrict__ feats, const float* __restrict__ bias,
    const int* __restrict__ tags, const P1Params& pp,
    float (&P)[4][NCOL], float (&lacc)[NCOL], float& gold, int& prev)
{
    const int t0c = c * TCH;
    #pragma unroll 1
    for (int bt = 0; bt < TCH / 8; ++bt) {
        const int t0 = t0c + bt * 8;
        float Fr[48];
        {
            const float4* fp4 = (const float4*)(feats + ((size_t)b * TN + t0) * 6);
            #pragma unroll
            for (int q = 0; q < 12; ++q) {
                const float4 vv = fp4[q];
                Fr[q*4+0] = vv.x; Fr[q*4+1] = vv.y; Fr[q*4+2] = vv.z; Fr[q*4+3] = vv.w;
            }
        }
        float Bv[8]; int Tg[8];
        {
            const float4* bp4 = (const float4*)(bias + (size_t)b * TN + t0);
            const float4 v0 = bp4[0], v1 = bp4[1];
            Bv[0]=v0.x; Bv[1]=v0.y; Bv[2]=v0.z; Bv[3]=v0.w;
            Bv[4]=v1.x; Bv[5]=v1.y; Bv[6]=v1.z; Bv[7]=v1.w;
            const int4* tp4 = (const int4*)(tags + (size_t)b * TN + t0);
            const int4 u0 = tp4[0], u1 = tp4[1];
            Tg[0]=u0.x; Tg[1]=u0.y; Tg[2]=u0.z; Tg[3]=u0.w;
            Tg[4]=u1.x; Tg[5]=u1.y; Tg[6]=u1.z; Tg[7]=u1.w;
        }
        #pragma unroll
        for (int s = 0; s < 8; ++s) {
            const float fi0 = Fr[s*6+0], fi1 = Fr[s*6+1];
            const float fi2 = Fr[s*6+2], fi3 = Fr[s*6+3];
            if (CHUNK0 && bt == 0 && s == 0) {
                const float a0 = fi0 + pp.tc4[0], a1 = fi1 + pp.tc4[1];
                const float a2 = fi2 + pp.tc4[2], a3 = fi3 + pp.tc4[3];
                const float mx = fmaxf(fmaxf(a0, a1), fmaxf(a2, a3));
                P[0][0] = ex2((a0 - mx) * kLog2e);
                P[1][0] = ex2((a1 - mx) * kLog2e);
                P[2][0] = ex2((a2 - mx) * kLog2e);
                P[3][0] = ex2((a3 - mx) * kLog2e);
                lacc[0] = mx * kLog2e;
                const int tg0 = Tg[0];
                gold = sel4(pp.tc4[0], pp.tc4[1], pp.tc4[2], pp.tc4[3], tg0)
                     + sel4(fi0, fi1, fi2, fi3, tg0);
                prev = tg0;
                continue;
            }
            step_generic<NCOL>(pp, fi0, fi1, fi2, fi3, Bv[s], Tg[s],
                               (s & 3) == 3, P, lacc, gold, prev);
        }
    }
}

template <int CCv>
__global__ void __launch_bounds__(256)
crf_phase1_fb(const float* __restrict__ feats, const float* __restrict__ bias,
              const int* __restrict__ tags, const float* __restrict__ trans,
              const float* __restrict__ wsh, const float* __restrict__ bno,
              const float* __restrict__ bwi, const float* __restrict__ wwo,
              const float* __restrict__ wno, const float* __restrict__ mult,
              float* __restrict__ matAll)
{
    constexpr int TCHv = TN / CCv;
    constexpr int BPB  = 256 / CCv;
    const int b = blockIdx.x * BPB + (threadIdx.x / CCv);
    const int c = threadIdx.x % CCv;

    __shared__ float sA[16], sM[16];
    if (threadIdx.x < 16) {
        const int i = threadIdx.x >> 2, j = threadIdx.x & 3;
        sA[threadIdx.x] = trans[i * 6 + j];
        const float m0 = mult[j], m1 = mult[4 + j], m2 = mult[8 + j], m3 = mult[12 + j];
        const float mx = fmaxf(fmaxf(m0, m1), fmaxf(m2, m3));
        const float e0 = ex2((m0 - mx) * kLog2e), e1 = ex2((m1 - mx) * kLog2e);
        const float e2 = ex2((m2 - mx) * kLog2e), e3 = ex2((m3 - mx) * kLog2e);
        const float inv = rcpf(e0 + e1 + e2 + e3);
        const float ei = (i == 0) ? e0 : (i == 1) ? e1 : (i == 2) ? e2 : e3;
        sM[threadIdx.x] = (i == j) ? -1.0f : ei * inv;
    }
    __syncthreads();

    P1Params pp;
    #pragma unroll
    for (int i = 0; i < 4; ++i)
        #pragma unroll
        for (int j = 0; j < 4; ++j) {
            pp.AL[i][j] = trans[i * 6 + j] * kLog2e;
            pp.M[i][j]  = sM[i * 4 + j];
        }
    #pragma unroll
    for (int j = 0; j < 4; ++j) { pp.wsv[j] = wsh[j]; pp.wwv[j] = wwo[j]; pp.wnv[j] = wno[j]; }
    pp.bwc = bwi[0]; pp.bnc = bno[0];
    pp.sA = sA; pp.sM = sM;
    pp.tc4[0] = trans[4]; pp.tc4[1] = trans[10]; pp.tc4[2] = trans[16]; pp.tc4[3] = trans[22];

    float o[SLOT];
    float gold = 0.0f;
    int prev;
    if (c == 0) {
        float P[4][1], lacc[1];
        run_chunk_fb<1, true, TCHv>(b, 0, feats, bias, tags, pp, P, lacc, gold, prev);
        #pragma unroll
        for (int i = 0; i < 4; ++i)
            #pragma unroll
            for (int j = 0; j < 4; ++j) o[i * 4 + j] = P[i][0];
        #pragma unroll
        for (int j = 0; j < 4; ++j) o[16 + j] = lacc[0];
    } else {
        float P[4][4], lacc[4] = {0.f, 0.f, 0.f, 0.f};
        #pragma unroll
        for (int i = 0; i < 4; ++i)
            #pragma unroll
            for (int j = 0; j < 4; ++j) P[i][j] = (i == j) ? 1.0f : 0.0f;
        prev = tags[(size_t)b * TN + c * TCHv - 1];
        run_chunk_fb<4, false, TCHv>(b, c, feats, bias, tags, pp, P, lacc, gold, prev);
        #pragma unroll
        for (int i = 0; i < 4; ++i)
            #pragma unroll
            for (int j = 0; j < 4; ++j) o[i * 4 + j] = P[i][j];
        #pragma unroll
        for (int j = 0; j < 4; ++j) o[16 + j] = lacc[j];
    }
    o[20] = gold; o[21] = 0.f; o[22] = 0.f; o[23] = 0.f;
    float4* s4 = (float4*)(matAll + ((size_t)b * CCv + c) * SLOT);
    #pragma unroll
    for (int q = 0; q < SLOT / 4; ++q)
        s4[q] = make_float4(o[4*q], o[4*q+1], o[4*q+2], o[4*q+3]);
}

template <int CCv>
__global__ void __launch_bounds__(256)
crf_phase2_fb(const float* __restrict__ matAll, const float* __restrict__ trans,
              const int* __restrict__ tags, float* __restrict__ out)
{
    constexpr int CPL = CCv / 64;
    const int gtid = blockIdx.x * 256 + threadIdx.x;
    const int b = gtid >> 6;
    const int lane = threadIdx.x & 63;

    const float4* base = (const float4*)(matAll + ((size_t)b * CCv + lane * CPL) * SLOT);
    float Pe[4][4], so[4], gold;
    {
        float A[SLOT];
        #pragma unroll
        for (int q = 0; q < SLOT / 4; ++q) {
            const float4 v = base[q];
            A[4*q] = v.x; A[4*q+1] = v.y; A[4*q+2] = v.z; A[4*q+3] = v.w;
        }
        #pragma unroll
        for (int i = 0; i < 4; ++i)
            #pragma unroll
            for (int j = 0; j < 4; ++j) Pe[i][j] = A[i * 4 + j];
        #pragma unroll
        for (int j = 0; j < 4; ++j) so[j] = A[16 + j];
        gold = A[20];
    }
    #pragma unroll
    for (int p = 1; p < CPL; ++p) {
        float A[SLOT];
        #pragma unroll
        for (int q = 0; q < SLOT / 4; ++q) {
            const float4 v = base[p * (SLOT / 4) + q];
            A[4*q] = v.x; A[4*q+1] = v.y; A[4*q+2] = v.z; A[4*q+3] = v.w;
        }
        float Ae[4][4], sa[4];
        #pragma unroll
        for (int i = 0; i < 4; ++i)
            #pragma unroll
            for (int j = 0; j < 4; ++j) Ae[i][j] = A[i * 4 + j];
        #pragma unroll
        for (int j = 0; j < 4; ++j) sa[j] = A[16 + j];
        gold += A[20];
        float Ce[4][4], sc[4];
        compose4(Ae, sa, Pe, so, Ce, sc);
        #pragma unroll
        for (int i = 0; i < 4; ++i)
            #pragma unroll
            for (int j = 0; j < 4; ++j) Pe[i][j] = Ce[i][j];
        #pragma unroll
        for (int j = 0; j < 4; ++j) so[j] = sc[j];
    }

    #pragma unroll
    for (int d = 1; d < 64; d <<= 1) {
        float oP[4][4], os[4];
        #pragma unroll
        for (int i = 0; i < 4; ++i)
            #pragma unroll
            for (int j = 0; j < 4; ++j) oP[i][j] = __shfl_xor(Pe[i][j], d, 64);
        #pragma unroll
        for (int j = 0; j < 4; ++j) os[j] = __shfl_xor(so[j], d, 64);
        const bool hi = (lane & d) != 0;
        float Ae[4][4], Be[4][4], sa[4], sb[4];
        #pragma unroll
        for (int i = 0; i < 4; ++i)
            #pragma unroll
            for (int j = 0; j < 4; ++j) {
                Ae[i][j] = hi ? Pe[i][j] : oP[i][j];
                Be[i][j] = hi ? oP[i][j] : Pe[i][j];
            }
        #pragma unroll
        for (int j = 0; j < 4; ++j) {
            sa[j] = hi ? so[j] : os[j];
            sb[j] = hi ? os[j] : so[j];
        }
        float Ce[4][4], sc[4];
        compose4(Ae, sa, Be, sb, Ce, sc);
        #pragma unroll
        for (int i = 0; i < 4; ++i)
            #pragma unroll
            for (int j = 0; j < 4; ++j) Pe[i][j] = Ce[i][j];
        #pragma unroll
        for (int j = 0; j < 4; ++j) so[j] = sc[j];
    }

    #pragma unroll
    for (int d = 1; d < 64; d <<= 1) gold += __shfl_xor(gold, d, 64);

    if (lane == 0) {
        const float t50 = trans[30], t51 = trans[31], t52 = trans[32], t53 = trans[33];
        const float ssum = Pe[0][0] * ex2(t50 * kLog2e) + Pe[1][0] * ex2(t51 * kLog2e)
                         + Pe[2][0] * ex2(t52 * kLog2e) + Pe[3][0] * ex2(t53 * kLog2e);
        const float fwd = (so[0] + lg2(ssum)) * kLn2;
        const int lastT = tags[(size_t)b * TN + TN - 1];
        const float gfin = gold + sel4(t50, t51, t52, t53, lastT);
        out[b] = fwd - gfin;
    }
}

extern "C" void kernel_launch(void* const* d_in, const int* in_sizes, int n_in,
                              void* d_out, int out_size, void* d_ws, size_t ws_size,
                              hipStream_t stream)
{
    const float* feats = (const float*)d_in[0];
    const float* bias  = (const float*)d_in[1];
    const int*   tags  = (const int*)d_in[2];
    const float* trans = (const float*)d_in[3];
    const float* wsh   = (const float*)d_in[4];
    const float* bno   = (const float*)d_in[5];
    const float* bwi   = (const float*)d_in[6];
    const float* wwo   = (const float*)d_in[7];
    const float* wno   = (const float*)d_in[8];
    const float* mult  = (const float*)d_in[9];
    float* out = (float*)d_out;
    float* matAll = (float*)d_ws;

    const size_t need256 = (size_t)BN * 256 * SLOT * sizeof(float);  // 50.3 MB
    const size_t need128 = (size_t)BN * 128 * SLOT * sizeof(float);  // 25.2 MB
    if (ws_size >= need256) {
        crf_phase1_t<<<BN, 256, 0, stream>>>(
            feats, bias, tags, trans, wsh, bno, bwi, wwo, wno, mult, matAll);
        crf_phase2_t<<<BN, 256, 0, stream>>>(matAll, trans, tags, out);
    } else if (ws_size >= need128) {
        crf_phase1_fb<128><<<(128 * BN) / 256, 256, 0, stream>>>(
            feats, bias, tags, trans, wsh, bno, bwi, wwo, wno, mult, matAll);
        crf_phase2_fb<128><<<(BN * 64) / 256, 256, 0, stream>>>(matAll, trans, tags, out);
    } else {
        crf_phase1_fb<64><<<(64 * BN) / 256, 256, 0, stream>>>(
            feats, bias, tags, trans, wsh, bno, bwi, wwo, wno, mult, matAll);
        crf_phase2_fb<64><<<(BN * 64) / 256, 256, 0, stream>>>(matAll, trans, tags, out);
    }
}

// Round 3
// 309.963 us; speedup vs baseline: 1.1432x; 1.1432x over previous
//
#include <hip/hip_runtime.h>

#define BN 2048   // batch
#define TN 2048   // time
#define SLOT 24   // floats per (b,chunk) result slot (16 P + 4 off + 1 gold + 3 pad)

__device__ __forceinline__ float ex2(float x){ return __builtin_amdgcn_exp2f(x); }
__device__ __forceinline__ float lg2(float x){ return __builtin_amdgcn_logf(x); }
__device__ __forceinline__ float rcpf(float x){ return __builtin_amdgcn_rcpf(x); }

constexpr float kLog2e = 1.4426950408889634f;
constexpr float kLn2   = 0.6931471805599453f;

__device__ __forceinline__ float fast_tanh(float x){
    float ax = fabsf(x);
    float e  = ex2(ax * (-2.0f * kLog2e));     // exp(-2|x|)
    float t  = (1.0f - e) * rcpf(1.0f + e);
    return copysignf(t, x);
}

__device__ __forceinline__ float sel4(float v0, float v1, float v2, float v3, int idx){
    float r = (idx == 1) ? v1 : v0;
    r = (idx == 2) ? v2 : r;
    r = (idx == 3) ? v3 : r;
    return r;
}

struct P1Params {
    float AL[4][4], M[4][4];
    float wsv[4], wwv[4], wnv[4];
    float bwc, bnc;
    const float* sA; const float* sM;
    float tc4[4];
};

// one generic CRF step (exp-space, NCOL alpha columns)
template <int NCOL>
__device__ __forceinline__ void step_generic(
    const P1Params& pp, float fi0, float fi1, float fi2, float fi3,
    float bv, int tg, bool renorm,
    float (&P)[4][NCOL], float (&lacc)[NCOL], float& gold, int& prev)
{
    const bool hw = bv > 0.5f;
    const float bc = hw ? pp.bwc : pp.bnc;
    float g[4], gL[4];
    #pragma unroll
    for (int j = 0; j < 4; ++j) {
        float x = fmaf(bv, pp.wsv[j], bc);
        g[j]  = (hw ? pp.wwv[j] : pp.wnv[j]) * fast_tanh(x);
        gL[j] = g[j] * kLog2e;
    }
    const float fiL[4] = { fi0 * kLog2e, fi1 * kLog2e, fi2 * kLog2e, fi3 * kLog2e };
    float nP[4][NCOL];
    #pragma unroll
    for (int i = 0; i < 4; ++i)
        #pragma unroll
        for (int j = 0; j < NCOL; ++j) nP[i][j] = 0.0f;
    #pragma unroll
    for (int k = 0; k < 4; ++k) {
        float Ek[4];
        #pragma unroll
        for (int i = 0; i < 4; ++i)
            Ek[i] = ex2(fmaf(gL[k], pp.M[i][k], fiL[i] + pp.AL[i][k]));
        #pragma unroll
        for (int j = 0; j < NCOL; ++j) {
            const float pk = P[k][j];
            #pragma unroll
            for (int i = 0; i < 4; ++i) nP[i][j] = fmaf(Ek[i], pk, nP[i][j]);
        }
    }
    #pragma unroll
    for (int i = 0; i < 4; ++i)
        #pragma unroll
        for (int j = 0; j < NCOL; ++j) P[i][j] = nP[i][j];

    const int idx = tg * 4 + prev;
    gold += pp.sA[idx] + sel4(g[0], g[1], g[2], g[3], prev) * pp.sM[idx]
          + sel4(fi0, fi1, fi2, fi3, tg);
    prev = tg;

    if (renorm) {     // exact pow2 renorm
        #pragma unroll
        for (int j = 0; j < NCOL; ++j) {
            float m = fmaxf(fmaxf(P[0][j], P[1][j]), fmaxf(P[2][j], P[3][j]));
            int ee = (int)((__float_as_uint(m) >> 23) & 255u) - 126;
            float sc = __uint_as_float((unsigned)(127 - ee) << 23);
            lacc[j] += (float)ee;
            #pragma unroll
            for (int i = 0; i < 4; ++i) P[i][j] *= sc;
        }
    }
}

// 8 steps of one chunk; feats held in 12 float4 registers
template <int NCOL, bool C0>
__device__ __forceinline__ void trip8(
    const float4 (&myF)[12], const float (&Bv)[8], const int (&Tg)[8],
    const P1Params& pp,
    float (&P)[4][NCOL], float (&lacc)[NCOL], float& gold, int& prev)
{
    #pragma unroll
    for (int p = 0; p < 4; ++p) {
        const float4 fA = myF[3*p], fB = myF[3*p+1], fC = myF[3*p+2];
        {   // step s = 2p : floats 12p+0..3 = fA.xyzw
            const float fi0 = fA.x, fi1 = fA.y, fi2 = fA.z, fi3 = fA.w;
            if (C0 && p == 0) {
                // closed-form t=0: alpha1[i] = f[0,i] + trans[i,START]
                const float a0 = fi0 + pp.tc4[0], a1 = fi1 + pp.tc4[1];
                const float a2 = fi2 + pp.tc4[2], a3 = fi3 + pp.tc4[3];
                const float mx = fmaxf(fmaxf(a0, a1), fmaxf(a2, a3));
                P[0][0] = ex2((a0 - mx) * kLog2e);
                P[1][0] = ex2((a1 - mx) * kLog2e);
                P[2][0] = ex2((a2 - mx) * kLog2e);
                P[3][0] = ex2((a3 - mx) * kLog2e);
                lacc[0] = mx * kLog2e;
                const int tg0 = Tg[0];
                gold = sel4(pp.tc4[0], pp.tc4[1], pp.tc4[2], pp.tc4[3], tg0)
                     + sel4(fi0, fi1, fi2, fi3, tg0);
                prev = tg0;
            } else {
                step_generic<NCOL>(pp, fi0, fi1, fi2, fi3, Bv[2*p], Tg[2*p],
                                   ((2*p) & 3) == 3, P, lacc, gold, prev);
            }
        }
        {   // step s = 2p+1 : floats 12p+6..9 = fB.zw, fC.xy
            const float fi0 = fB.z, fi1 = fB.w, fi2 = fC.x, fi3 = fC.y;
            step_generic<NCOL>(pp, fi0, fi1, fi2, fi3, Bv[2*p+1], Tg[2*p+1],
                               ((2*p+1) & 3) == 3, P, lacc, gold, prev);
        }
    }
}

// ============ CC=256 primary: 1 block = 1 batch, 4 waves x 64 chunks ============
// All global access coalesced; lane-transpose via wave-private LDS (ds_write/ds_read).
__global__ void __launch_bounds__(256, 3)
crf_phase1_t(const float* __restrict__ feats, const float* __restrict__ bias,
             const int* __restrict__ tags, const float* __restrict__ trans,
             const float* __restrict__ wsh, const float* __restrict__ bno,
             const float* __restrict__ bwi, const float* __restrict__ wwo,
             const float* __restrict__ wno, const float* __restrict__ mult,
             float* __restrict__ matAll)
{
    constexpr int CC = 256;
    const int w = threadIdx.x >> 6;     // wave 0..3
    const int L = threadIdx.x & 63;     // lane = local chunk
    const int b = blockIdx.x;
    const int c = threadIdx.x;          // global chunk id 0..255

    __shared__ float4 stage[4][768];    // 12 KB per wave (wave-private)
    __shared__ float sA[16], sM[16];
    float4* stageW = stage[w];

    // ---- issue all global loads up front (all lane-consecutive) ----
    float4 tF[12];
    {
        const float4* gF = (const float4*)(feats + ((size_t)b * TN + (size_t)w * 512) * 6);
        #pragma unroll
        for (int r = 0; r < 12; ++r) tF[r] = gF[r * 64 + L];
    }
    float4 tB[2];
    {
        const float4* gB = (const float4*)(bias + (size_t)b * TN + (size_t)w * 512);
        tB[0] = gB[L]; tB[1] = gB[64 + L];
    }
    int4 tT[2];
    {
        const int4* gT = (const int4*)(tags + (size_t)b * TN + (size_t)w * 512);
        tT[0] = gT[L]; tT[1] = gT[64 + L];
    }
    int prevL0 = 0;
    if (L == 0 && threadIdx.x != 0)
        prevL0 = tags[(size_t)b * TN + (size_t)c * 8 - 1];

    if (threadIdx.x < 16) {
        const int i = threadIdx.x >> 2, j = threadIdx.x & 3;
        sA[threadIdx.x] = trans[i * 6 + j];
        const float m0 = mult[j], m1 = mult[4 + j], m2 = mult[8 + j], m3 = mult[12 + j];
        const float mx = fmaxf(fmaxf(m0, m1), fmaxf(m2, m3));
        const float e0 = ex2((m0 - mx) * kLog2e), e1 = ex2((m1 - mx) * kLog2e);
        const float e2 = ex2((m2 - mx) * kLog2e), e3 = ex2((m3 - mx) * kLog2e);
        const float inv = rcpf(e0 + e1 + e2 + e3);
        const float ei = (i == 0) ? e0 : (i == 1) ? e1 : (i == 2) ? e2 : e3;
        sM[threadIdx.x] = (i == j) ? -1.0f : ei * inv;
    }
    __syncthreads();

    // ---- feats transpose: plane-major with +p rotation (conflict-light) ----
    #pragma unroll
    for (int r = 0; r < 12; ++r) {
        const int S  = r * 64 + L;
        const int cS = (S * 2731) >> 15;          // S/12, exact for S<768
        const int p  = S - cS * 12;
        stageW[(p << 6) + ((cS + p) & 63)] = tF[r];
    }
    float4 myF[12];
    #pragma unroll
    for (int p = 0; p < 12; ++p)
        myF[p] = stageW[(p << 6) + ((L + p) & 63)];

    // ---- bias/tags transpose (reuse slots 0..255; WAR ordered by lgkmcnt) ----
    #pragma unroll
    for (int r = 0; r < 2; ++r) {
        const int S = r * 64 + L;
        stageW[((S & 1) << 6) + (S >> 1)] = tB[r];
        ((int4*)stageW)[128 + ((S & 1) << 6) + (S >> 1)] = tT[r];
    }
    float Bv[8]; int Tg[8];
    {
        const float4 b0 = stageW[L], b1 = stageW[64 + L];
        Bv[0]=b0.x; Bv[1]=b0.y; Bv[2]=b0.z; Bv[3]=b0.w;
        Bv[4]=b1.x; Bv[5]=b1.y; Bv[6]=b1.z; Bv[7]=b1.w;
        const int4 t0 = ((const int4*)stageW)[128 + L], t1 = ((const int4*)stageW)[192 + L];
        Tg[0]=t0.x; Tg[1]=t0.y; Tg[2]=t0.z; Tg[3]=t0.w;
        Tg[4]=t1.x; Tg[5]=t1.y; Tg[6]=t1.z; Tg[7]=t1.w;
    }
    // prev tag: neighbor lane's last staged tag (lane 0: the 1 scalar load)
    int prev = __shfl(Tg[7], L - 1, 64);
    if (L == 0) prev = prevL0;

    P1Params pp;
    #pragma unroll
    for (int i = 0; i < 4; ++i)
        #pragma unroll
        for (int j = 0; j < 4; ++j) {
            pp.AL[i][j] = trans[i * 6 + j] * kLog2e;
            pp.M[i][j]  = sM[i * 4 + j];
        }
    #pragma unroll
    for (int j = 0; j < 4; ++j) { pp.wsv[j] = wsh[j]; pp.wwv[j] = wwo[j]; pp.wnv[j] = wno[j]; }
    pp.bwc = bwi[0]; pp.bnc = bno[0];
    pp.sA = sA; pp.sM = sM;
    pp.tc4[0] = trans[4]; pp.tc4[1] = trans[10]; pp.tc4[2] = trans[16]; pp.tc4[3] = trans[22];

    float o[SLOT];
    float gold = 0.0f;
    if (c == 0) {
        float P[4][1], lacc[1];
        trip8<1, true>(myF, Bv, Tg, pp, P, lacc, gold, prev);
        #pragma unroll
        for (int i = 0; i < 4; ++i)
            #pragma unroll
            for (int j = 0; j < 4; ++j) o[i * 4 + j] = P[i][0];   // rank-1 lift
        #pragma unroll
        for (int j = 0; j < 4; ++j) o[16 + j] = lacc[0];
    } else {
        float P[4][4], lacc[4] = {0.f, 0.f, 0.f, 0.f};
        #pragma unroll
        for (int i = 0; i < 4; ++i)
            #pragma unroll
            for (int j = 0; j < 4; ++j) P[i][j] = (i == j) ? 1.0f : 0.0f;
        trip8<4, false>(myF, Bv, Tg, pp, P, lacc, gold, prev);
        #pragma unroll
        for (int i = 0; i < 4; ++i)
            #pragma unroll
            for (int j = 0; j < 4; ++j) o[i * 4 + j] = P[i][j];
        #pragma unroll
        for (int j = 0; j < 4; ++j) o[16 + j] = lacc[j];
    }
    o[20] = gold; o[21] = 0.f; o[22] = 0.f; o[23] = 0.f;

    // ---- store bounce: SLOT-major global layout (same as round-1), coalesced ----
    #pragma unroll
    for (int q = 0; q < 6; ++q)
        stageW[(q << 6) + L] = make_float4(o[4*q], o[4*q+1], o[4*q+2], o[4*q+3]);
    float4* gout = (float4*)matAll + ((size_t)b * CC + (size_t)w * 64) * 6;
    #pragma unroll
    for (int r = 0; r < 6; ++r) {
        const int G  = r * 64 + L;
        const int cS = (G * 5462) >> 15;          // G/6, exact for G<768
        const int q  = G - cS * 6;
        gout[G] = stageW[(q << 6) + cS];
    }
}

// C = A∘B (A later, B earlier) in exp-space with per-column base-2 offsets.
__device__ __forceinline__ void compose4(
    const float (&Ae)[4][4], const float (&sa)[4],
    const float (&Be)[4][4], const float (&sb)[4],
    float (&Ce)[4][4], float (&sc)[4])
{
    const float maxA = fmaxf(fmaxf(sa[0], sa[1]), fmaxf(sa[2], sa[3]));
    float Ap[4][4];
    #pragma unroll
    for (int k = 0; k < 4; ++k) {
        const float wk = ex2(sa[k] - maxA);
        #pragma unroll
        for (int i = 0; i < 4; ++i) Ap[i][k] = Ae[i][k] * wk;
    }
    #pragma unroll
    for (int j = 0; j < 4; ++j) {
        float c0 = 0.f, c1 = 0.f, c2 = 0.f, c3 = 0.f;
        #pragma unroll
        for (int k = 0; k < 4; ++k) {
            const float bk = Be[k][j];
            c0 = fmaf(Ap[0][k], bk, c0);
            c1 = fmaf(Ap[1][k], bk, c1);
            c2 = fmaf(Ap[2][k], bk, c2);
            c3 = fmaf(Ap[3][k], bk, c3);
        }
        const float m = fmaxf(fmaxf(c0, c1), fmaxf(c2, c3));
        const int ee = (int)((__float_as_uint(m) >> 23) & 255u) - 126;
        const float scf = __uint_as_float((unsigned)(127 - ee) << 23);
        Ce[0][j] = c0 * scf; Ce[1][j] = c1 * scf;
        Ce[2][j] = c2 * scf; Ce[3][j] = c3 * scf;
        sc[j] = sb[j] + maxA + (float)ee;
    }
}

// phase2 (round-1 proven): lane holds CPL consecutive chunks, serial pre-compose,
// then in-wave ordered shuffle tree.
template <int CCv>
__global__ void __launch_bounds__(256)
crf_phase2(const float* __restrict__ matAll, const float* __restrict__ trans,
           const int* __restrict__ tags, float* __restrict__ out)
{
    constexpr int CPL = CCv / 64;
    const int gtid = blockIdx.x * 256 + threadIdx.x;
    const int b = gtid >> 6;
    const int lane = threadIdx.x & 63;

    const float4* base = (const float4*)(matAll + ((size_t)b * CCv + lane * CPL) * SLOT);
    float Pe[4][4], so[4], gold;
    {
        float A[SLOT];
        #pragma unroll
        for (int q = 0; q < SLOT / 4; ++q) {
            const float4 v = base[q];
            A[4*q] = v.x; A[4*q+1] = v.y; A[4*q+2] = v.z; A[4*q+3] = v.w;
        }
        #pragma unroll
        for (int i = 0; i < 4; ++i)
            #pragma unroll
            for (int j = 0; j < 4; ++j) Pe[i][j] = A[i * 4 + j];
        #pragma unroll
        for (int j = 0; j < 4; ++j) so[j] = A[16 + j];
        gold = A[20];
    }
    #pragma unroll
    for (int p = 1; p < CPL; ++p) {
        float A[SLOT];
        #pragma unroll
        for (int q = 0; q < SLOT / 4; ++q) {
            const float4 v = base[p * (SLOT / 4) + q];
            A[4*q] = v.x; A[4*q+1] = v.y; A[4*q+2] = v.z; A[4*q+3] = v.w;
        }
        float Ae[4][4], sa[4];
        #pragma unroll
        for (int i = 0; i < 4; ++i)
            #pragma unroll
            for (int j = 0; j < 4; ++j) Ae[i][j] = A[i * 4 + j];
        #pragma unroll
        for (int j = 0; j < 4; ++j) sa[j] = A[16 + j];
        gold += A[20];
        float Ce[4][4], sc[4];
        compose4(Ae, sa, Pe, so, Ce, sc);     // A is the later chunk
        #pragma unroll
        for (int i = 0; i < 4; ++i)
            #pragma unroll
            for (int j = 0; j < 4; ++j) Pe[i][j] = Ce[i][j];
        #pragma unroll
        for (int j = 0; j < 4; ++j) so[j] = sc[j];
    }

    #pragma unroll
    for (int d = 1; d < 64; d <<= 1) {
        float oP[4][4], os[4];
        #pragma unroll
        for (int i = 0; i < 4; ++i)
            #pragma unroll
            for (int j = 0; j < 4; ++j) oP[i][j] = __shfl_xor(Pe[i][j], d, 64);
        #pragma unroll
        for (int j = 0; j < 4; ++j) os[j] = __shfl_xor(so[j], d, 64);
        const bool hi = (lane & d) != 0;
        float Ae[4][4], Be[4][4], sa[4], sb[4];
        #pragma unroll
        for (int i = 0; i < 4; ++i)
            #pragma unroll
            for (int j = 0; j < 4; ++j) {
                Ae[i][j] = hi ? Pe[i][j] : oP[i][j];
                Be[i][j] = hi ? oP[i][j] : Pe[i][j];
            }
        #pragma unroll
        for (int j = 0; j < 4; ++j) {
            sa[j] = hi ? so[j] : os[j];
            sb[j] = hi ? os[j] : so[j];
        }
        float Ce[4][4], sc[4];
        compose4(Ae, sa, Be, sb, Ce, sc);
        #pragma unroll
        for (int i = 0; i < 4; ++i)
            #pragma unroll
            for (int j = 0; j < 4; ++j) Pe[i][j] = Ce[i][j];
        #pragma unroll
        for (int j = 0; j < 4; ++j) so[j] = sc[j];
    }

    #pragma unroll
    for (int d = 1; d < 64; d <<= 1) gold += __shfl_xor(gold, d, 64);

    if (lane == 0) {
        const float t50 = trans[30], t51 = trans[31], t52 = trans[32], t53 = trans[33];
        const float ssum = Pe[0][0] * ex2(t50 * kLog2e) + Pe[1][0] * ex2(t51 * kLog2e)
                         + Pe[2][0] * ex2(t52 * kLog2e) + Pe[3][0] * ex2(t53 * kLog2e);
        const float fwd = (so[0] + lg2(ssum)) * kLn2;
        const int lastT = tags[(size_t)b * TN + TN - 1];
        const float gfin = gold + sel4(t50, t51, t52, t53, lastT);
        out[b] = fwd - gfin;
    }
}

// ==================== fallback (round-1 kernels, small workspace) ====================
template <int NCOL, bool CHUNK0, int TCH>
__device__ __forceinline__ void run_chunk_fb(
    int b, int c,
    const float* __restrict__ feats, const float* __restrict__ bias,
    const int* __restrict__ tags, const P1Params& pp,
    float (&P)[4][NCOL], float (&lacc)[NCOL], float& gold, int& prev)
{
    const int t0c = c * TCH;
    #pragma unroll 1
    for (int bt = 0; bt < TCH / 8; ++bt) {
        const int t0 = t0c + bt * 8;
        float Fr[48];
        {
            const float4* fp4 = (const float4*)(feats + ((size_t)b * TN + t0) * 6);
            #pragma unroll
            for (int q = 0; q < 12; ++q) {
                const float4 vv = fp4[q];
                Fr[q*4+0] = vv.x; Fr[q*4+1] = vv.y; Fr[q*4+2] = vv.z; Fr[q*4+3] = vv.w;
            }
        }
        float Bv[8]; int Tg[8];
        {
            const float4* bp4 = (const float4*)(bias + (size_t)b * TN + t0);
            const float4 v0 = bp4[0], v1 = bp4[1];
            Bv[0]=v0.x; Bv[1]=v0.y; Bv[2]=v0.z; Bv[3]=v0.w;
            Bv[4]=v1.x; Bv[5]=v1.y; Bv[6]=v1.z; Bv[7]=v1.w;
            const int4* tp4 = (const int4*)(tags + (size_t)b * TN + t0);
            const int4 u0 = tp4[0], u1 = tp4[1];
            Tg[0]=u0.x; Tg[1]=u0.y; Tg[2]=u0.z; Tg[3]=u0.w;
            Tg[4]=u1.x; Tg[5]=u1.y; Tg[6]=u1.z; Tg[7]=u1.w;
        }
        #pragma unroll
        for (int s = 0; s < 8; ++s) {
            const float fi0 = Fr[s*6+0], fi1 = Fr[s*6+1];
            const float fi2 = Fr[s*6+2], fi3 = Fr[s*6+3];
            if (CHUNK0 && bt == 0 && s == 0) {
                const float a0 = fi0 + pp.tc4[0], a1 = fi1 + pp.tc4[1];
                const float a2 = fi2 + pp.tc4[2], a3 = fi3 + pp.tc4[3];
                const float mx = fmaxf(fmaxf(a0, a1), fmaxf(a2, a3));
                P[0][0] = ex2((a0 - mx) * kLog2e);
                P[1][0] = ex2((a1 - mx) * kLog2e);
                P[2][0] = ex2((a2 - mx) * kLog2e);
                P[3][0] = ex2((a3 - mx) * kLog2e);
                lacc[0] = mx * kLog2e;
                const int tg0 = Tg[0];
                gold = sel4(pp.tc4[0], pp.tc4[1], pp.tc4[2], pp.tc4[3], tg0)
                     + sel4(fi0, fi1, fi2, fi3, tg0);
                prev = tg0;
                continue;
            }
            step_generic<NCOL>(pp, fi0, fi1, fi2, fi3, Bv[s], Tg[s],
                               (s & 3) == 3, P, lacc, gold, prev);
        }
    }
}

template <int CCv>
__global__ void __launch_bounds__(256)
crf_phase1_fb(const float* __restrict__ feats, const float* __restrict__ bias,
              const int* __restrict__ tags, const float* __restrict__ trans,
              const float* __restrict__ wsh, const float* __restrict__ bno,
              const float* __restrict__ bwi, const float* __restrict__ wwo,
              const float* __restrict__ wno, const float* __restrict__ mult,
              float* __restrict__ matAll)
{
    constexpr int TCHv = TN / CCv;
    constexpr int BPB  = 256 / CCv;
    const int b = blockIdx.x * BPB + (threadIdx.x / CCv);
    const int c = threadIdx.x % CCv;

    __shared__ float sA[16], sM[16];
    if (threadIdx.x < 16) {
        const int i = threadIdx.x >> 2, j = threadIdx.x & 3;
        sA[threadIdx.x] = trans[i * 6 + j];
        const float m0 = mult[j], m1 = mult[4 + j], m2 = mult[8 + j], m3 = mult[12 + j];
        const float mx = fmaxf(fmaxf(m0, m1), fmaxf(m2, m3));
        const float e0 = ex2((m0 - mx) * kLog2e), e1 = ex2((m1 - mx) * kLog2e);
        const float e2 = ex2((m2 - mx) * kLog2e), e3 = ex2((m3 - mx) * kLog2e);
        const float inv = rcpf(e0 + e1 + e2 + e3);
        const float ei = (i == 0) ? e0 : (i == 1) ? e1 : (i == 2) ? e2 : e3;
        sM[threadIdx.x] = (i == j) ? -1.0f : ei * inv;
    }
    __syncthreads();

    P1Params pp;
    #pragma unroll
    for (int i = 0; i < 4; ++i)
        #pragma unroll
        for (int j = 0; j < 4; ++j) {
            pp.AL[i][j] = trans[i * 6 + j] * kLog2e;
            pp.M[i][j]  = sM[i * 4 + j];
        }
    #pragma unroll
    for (int j = 0; j < 4; ++j) { pp.wsv[j] = wsh[j]; pp.wwv[j] = wwo[j]; pp.wnv[j] = wno[j]; }
    pp.bwc = bwi[0]; pp.bnc = bno[0];
    pp.sA = sA; pp.sM = sM;
    pp.tc4[0] = trans[4]; pp.tc4[1] = trans[10]; pp.tc4[2] = trans[16]; pp.tc4[3] = trans[22];

    float o[SLOT];
    float gold = 0.0f;
    int prev;
    if (c == 0) {
        float P[4][1], lacc[1];
        run_chunk_fb<1, true, TCHv>(b, 0, feats, bias, tags, pp, P, lacc, gold, prev);
        #pragma unroll
        for (int i = 0; i < 4; ++i)
            #pragma unroll
            for (int j = 0; j < 4; ++j) o[i * 4 + j] = P[i][0];
        #pragma unroll
        for (int j = 0; j < 4; ++j) o[16 + j] = lacc[0];
    } else {
        float P[4][4], lacc[4] = {0.f, 0.f, 0.f, 0.f};
        #pragma unroll
        for (int i = 0; i < 4; ++i)
            #pragma unroll
            for (int j = 0; j < 4; ++j) P[i][j] = (i == j) ? 1.0f : 0.0f;
        prev = tags[(size_t)b * TN + c * TCHv - 1];
        run_chunk_fb<4, false, TCHv>(b, c, feats, bias, tags, pp, P, lacc, gold, prev);
        #pragma unroll
        for (int i = 0; i < 4; ++i)
            #pragma unroll
            for (int j = 0; j < 4; ++j) o[i * 4 + j] = P[i][j];
        #pragma unroll
        for (int j = 0; j < 4; ++j) o[16 + j] = lacc[j];
    }
    o[20] = gold; o[21] = 0.f; o[22] = 0.f; o[23] = 0.f;
    float4* s4 = (float4*)(matAll + ((size_t)b * CCv + c) * SLOT);
    #pragma unroll
    for (int q = 0; q < SLOT / 4; ++q)
        s4[q] = make_float4(o[4*q], o[4*q+1], o[4*q+2], o[4*q+3]);
}

extern "C" void kernel_launch(void* const* d_in, const int* in_sizes, int n_in,
                              void* d_out, int out_size, void* d_ws, size_t ws_size,
                              hipStream_t stream)
{
    const float* feats = (const float*)d_in[0];
    const float* bias  = (const float*)d_in[1];
    const int*   tags  = (const int*)d_in[2];
    const float* trans = (const float*)d_in[3];
    const float* wsh   = (const float*)d_in[4];
    const float* bno   = (const float*)d_in[5];
    const float* bwi   = (const float*)d_in[6];
    const float* wwo   = (const float*)d_in[7];
    const float* wno   = (const float*)d_in[8];
    const float* mult  = (const float*)d_in[9];
    float* out = (float*)d_out;
    float* matAll = (float*)d_ws;

    const size_t need256 = (size_t)BN * 256 * SLOT * sizeof(float);  // 50.3 MB
    const size_t need128 = (size_t)BN * 128 * SLOT * sizeof(float);  // 25.2 MB
    if (ws_size >= need256) {
        crf_phase1_t<<<BN, 256, 0, stream>>>(
            feats, bias, tags, trans, wsh, bno, bwi, wwo, wno, mult, matAll);
        crf_phase2<256><<<(BN * 64) / 256, 256, 0, stream>>>(matAll, trans, tags, out);
    } else if (ws_size >= need128) {
        crf_phase1_fb<128><<<(128 * BN) / 256, 256, 0, stream>>>(
            feats, bias, tags, trans, wsh, bno, bwi, wwo, wno, mult, matAll);
        crf_phase2<128><<<(BN * 64) / 256, 256, 0, stream>>>(matAll, trans, tags, out);
    } else {
        crf_phase1_fb<64><<<(64 * BN) / 256, 256, 0, stream>>>(
            feats, bias, tags, trans, wsh, bno, bwi, wwo, wno, mult, matAll);
        crf_phase2<64><<<(BN * 64) / 256, 256, 0, stream>>>(matAll, trans, tags, out);
    }
}

// Round 4
// 227.713 us; speedup vs baseline: 1.5561x; 1.3612x over previous
//
#include <hip/hip_runtime.h>

#define BN 2048   // batch
#define TN 2048   // time
#define SLOT 24   // floats per (b,chunk) result slot (16 P + 4 off + 1 gold + 3 pad)

__device__ __forceinline__ float ex2(float x){ return __builtin_amdgcn_exp2f(x); }
__device__ __forceinline__ float lg2(float x){ return __builtin_amdgcn_logf(x); }
__device__ __forceinline__ float rcpf(float x){ return __builtin_amdgcn_rcpf(x); }

constexpr float kLog2e = 1.4426950408889634f;
constexpr float kLn2   = 0.6931471805599453f;

__device__ __forceinline__ float fast_tanh(float x){
    float ax = fabsf(x);
    float e  = ex2(ax * (-2.0f * kLog2e));     // exp(-2|x|)
    float t  = (1.0f - e) * rcpf(1.0f + e);
    return copysignf(t, x);
}

__device__ __forceinline__ float sel4(float v0, float v1, float v2, float v3, int idx){
    float r = (idx == 1) ? v1 : v0;
    r = (idx == 2) ? v2 : r;
    r = (idx == 3) ? v3 : r;
    return r;
}

struct P1Params {
    float AL[4][4], M[4][4];
    float wsv[4], wwv[4], wnv[4];
    float bwc, bnc;
    const float* sA; const float* sM;
    float tc4[4];
};

// one generic CRF step (exp-space, NCOL alpha columns)
template <int NCOL>
__device__ __forceinline__ void step_generic(
    const P1Params& pp, float fi0, float fi1, float fi2, float fi3,
    float bv, int tg, bool renorm,
    float (&P)[4][NCOL], float (&lacc)[NCOL], float& gold, int& prev)
{
    const bool hw = bv > 0.5f;
    const float bc = hw ? pp.bwc : pp.bnc;
    float g[4], gL[4];
    #pragma unroll
    for (int j = 0; j < 4; ++j) {
        float x = fmaf(bv, pp.wsv[j], bc);
        g[j]  = (hw ? pp.wwv[j] : pp.wnv[j]) * fast_tanh(x);
        gL[j] = g[j] * kLog2e;
    }
    const float fiL[4] = { fi0 * kLog2e, fi1 * kLog2e, fi2 * kLog2e, fi3 * kLog2e };
    float nP[4][NCOL];
    #pragma unroll
    for (int i = 0; i < 4; ++i)
        #pragma unroll
        for (int j = 0; j < NCOL; ++j) nP[i][j] = 0.0f;
    #pragma unroll
    for (int k = 0; k < 4; ++k) {
        float Ek[4];
        #pragma unroll
        for (int i = 0; i < 4; ++i)
            Ek[i] = ex2(fmaf(gL[k], pp.M[i][k], fiL[i] + pp.AL[i][k]));
        #pragma unroll
        for (int j = 0; j < NCOL; ++j) {
            const float pk = P[k][j];
            #pragma unroll
            for (int i = 0; i < 4; ++i) nP[i][j] = fmaf(Ek[i], pk, nP[i][j]);
        }
    }
    #pragma unroll
    for (int i = 0; i < 4; ++i)
        #pragma unroll
        for (int j = 0; j < NCOL; ++j) P[i][j] = nP[i][j];

    const int idx = tg * 4 + prev;
    gold += pp.sA[idx] + sel4(g[0], g[1], g[2], g[3], prev) * pp.sM[idx]
          + sel4(fi0, fi1, fi2, fi3, tg);
    prev = tg;

    if (renorm) {     // exact pow2 renorm
        #pragma unroll
        for (int j = 0; j < NCOL; ++j) {
            float m = fmaxf(fmaxf(P[0][j], P[1][j]), fmaxf(P[2][j], P[3][j]));
            int ee = (int)((__float_as_uint(m) >> 23) & 255u) - 126;
            float sc = __uint_as_float((unsigned)(127 - ee) << 23);
            lacc[j] += (float)ee;
            #pragma unroll
            for (int i = 0; i < 4; ++i) P[i][j] *= sc;
        }
    }
}

// 4 steps (one half-chunk); feats in 6 float4 registers, renorm at local step 3
template <int NCOL, bool C0>
__device__ __forceinline__ void trip4(
    const float4 (&F)[6], const float (&Bv)[4], const int (&Tg)[4],
    const P1Params& pp, float (&P)[4][NCOL], float (&lacc)[NCOL],
    float& gold, int& prev)
{
    #pragma unroll
    for (int p = 0; p < 2; ++p) {
        const float4 fA = F[3*p], fB = F[3*p+1], fC = F[3*p+2];
        {   // local step 2p : floats 12p+0..3 = fA.xyzw
            const float fi0 = fA.x, fi1 = fA.y, fi2 = fA.z, fi3 = fA.w;
            if (C0 && p == 0) {
                // closed-form t=0: alpha1[i] = f[0,i] + trans[i,START]
                const float a0 = fi0 + pp.tc4[0], a1 = fi1 + pp.tc4[1];
                const float a2 = fi2 + pp.tc4[2], a3 = fi3 + pp.tc4[3];
                const float mx = fmaxf(fmaxf(a0, a1), fmaxf(a2, a3));
                P[0][0] = ex2((a0 - mx) * kLog2e);
                P[1][0] = ex2((a1 - mx) * kLog2e);
                P[2][0] = ex2((a2 - mx) * kLog2e);
                P[3][0] = ex2((a3 - mx) * kLog2e);
                lacc[0] = mx * kLog2e;
                const int tg0 = Tg[0];
                gold = sel4(pp.tc4[0], pp.tc4[1], pp.tc4[2], pp.tc4[3], tg0)
                     + sel4(fi0, fi1, fi2, fi3, tg0);
                prev = tg0;
            } else {
                step_generic<NCOL>(pp, fi0, fi1, fi2, fi3, Bv[2*p], Tg[2*p],
                                   false, P, lacc, gold, prev);
            }
        }
        {   // local step 2p+1 : floats 12p+6..9 = fB.zw, fC.xy
            const float fi0 = fB.z, fi1 = fB.w, fi2 = fC.x, fi3 = fC.y;
            step_generic<NCOL>(pp, fi0, fi1, fi2, fi3, Bv[2*p+1], Tg[2*p+1],
                               (2*p+1) == 3, P, lacc, gold, prev);
        }
    }
}

// ============ CC=256 primary: 1 block = 1 batch, 4 waves x 64 chunks ============
// Coalesced feats via wave-private LDS transpose, HALF-CHUNK at a time so only
// 6 float4 staging registers are ever live (round-2/3 spilled with 12+12).
__global__ void __launch_bounds__(256)
crf_phase1_t(const float* __restrict__ feats, const float* __restrict__ bias,
             const int* __restrict__ tags, const float* __restrict__ trans,
             const float* __restrict__ wsh, const float* __restrict__ bno,
             const float* __restrict__ bwi, const float* __restrict__ wwo,
             const float* __restrict__ wno, const float* __restrict__ mult,
             float* __restrict__ matAll)
{
    const int w = threadIdx.x >> 6;     // wave 0..3
    const int L = threadIdx.x & 63;     // lane = local chunk
    const int b = blockIdx.x;
    const int c = threadIdx.x;          // global chunk id 0..255

    __shared__ float4 stage[4 * 384];   // 6 KB per wave, wave-private
    __shared__ float sA[16], sM[16];
    float4* stageW = stage + w * 384;

    if (threadIdx.x < 16) {
        const int i = threadIdx.x >> 2, j = threadIdx.x & 3;
        sA[threadIdx.x] = trans[i * 6 + j];
        const float m0 = mult[j], m1 = mult[4 + j], m2 = mult[8 + j], m3 = mult[12 + j];
        const float mx = fmaxf(fmaxf(m0, m1), fmaxf(m2, m3));
        const float e0 = ex2((m0 - mx) * kLog2e), e1 = ex2((m1 - mx) * kLog2e);
        const float e2 = ex2((m2 - mx) * kLog2e), e3 = ex2((m3 - mx) * kLog2e);
        const float inv = rcpf(e0 + e1 + e2 + e3);
        const float ei = (i == 0) ? e0 : (i == 1) ? e1 : (i == 2) ? e2 : e3;
        sM[threadIdx.x] = (i == j) ? -1.0f : ei * inv;
    }
    __syncthreads();

    P1Params pp;
    #pragma unroll
    for (int i = 0; i < 4; ++i)
        #pragma unroll
        for (int j = 0; j < 4; ++j) {
            pp.AL[i][j] = trans[i * 6 + j] * kLog2e;
            pp.M[i][j]  = sM[i * 4 + j];
        }
    #pragma unroll
    for (int j = 0; j < 4; ++j) { pp.wsv[j] = wsh[j]; pp.wwv[j] = wwo[j]; pp.wnv[j] = wno[j]; }
    pp.bwc = bwi[0]; pp.bnc = bno[0];
    pp.sA = sA; pp.sM = sM;
    pp.tc4[0] = trans[4]; pp.tc4[1] = trans[10]; pp.tc4[2] = trans[16]; pp.tc4[3] = trans[22];

    // ---- bias/tags: per-lane direct (round-1 proven), split into halves ----
    float BvA[4], BvB[4]; int TgA[4], TgB[4];
    {
        const float4* bp = (const float4*)(bias + (size_t)b * TN + c * 8);
        const float4 b0 = bp[0], b1 = bp[1];
        BvA[0]=b0.x; BvA[1]=b0.y; BvA[2]=b0.z; BvA[3]=b0.w;
        BvB[0]=b1.x; BvB[1]=b1.y; BvB[2]=b1.z; BvB[3]=b1.w;
        const int4* tp = (const int4*)(tags + (size_t)b * TN + c * 8);
        const int4 t0 = tp[0], t1 = tp[1];
        TgA[0]=t0.x; TgA[1]=t0.y; TgA[2]=t0.z; TgA[3]=t0.w;
        TgB[0]=t1.x; TgB[1]=t1.y; TgB[2]=t1.z; TgB[3]=t1.w;
    }
    int prev = 0;
    if (c != 0) prev = tags[(size_t)b * TN + c * 8 - 1];

    // wave's feats window: 64 chunks x 12 float4, chunk cl owns [12*cl, 12*cl+12)
    const float4* gF = (const float4*)feats + (size_t)b * 3072 + (size_t)w * 768;

    float P1a[4][1], lacc1[1];
    float P4[4][4],  lacc4[4] = {0.f, 0.f, 0.f, 0.f};
    #pragma unroll
    for (int i = 0; i < 4; ++i)
        #pragma unroll
        for (int j = 0; j < 4; ++j) P4[i][j] = (i == j) ? 1.0f : 0.0f;
    float gold = 0.0f;

    #pragma unroll 1
    for (int h = 0; h < 2; ++h) {
        // ---- stage half-chunk: 6 strided-coalesced loads -> LDS transpose ----
        float4 myF[6];
        {
            float4 tF[6];
            const int h6 = h * 6;
            #pragma unroll
            for (int r = 0; r < 6; ++r) {
                const int S  = r * 64 + L;
                const int cS = (S * 10923) >> 16;     // S/6, exact for S<384
                const int j  = S - cS * 6;
                tF[r] = gF[cS * 12 + h6 + j];
            }
            #pragma unroll
            for (int r = 0; r < 6; ++r) {
                const int S  = r * 64 + L;
                const int cS = (S * 10923) >> 16;
                const int j  = S - cS * 6;
                stageW[(j << 6) + ((cS + j) & 63)] = tF[r];
            }
            #pragma unroll
            for (int j = 0; j < 6; ++j)
                myF[j] = stageW[(j << 6) + ((L + j) & 63)];
        }
        // ---- compute 4 steps (staging hoisted out of the divergent branch) ----
        if (c == 0) {
            if (h == 0) trip4<1, true >(myF, BvA, TgA, pp, P1a, lacc1, gold, prev);
            else        trip4<1, false>(myF, BvB, TgB, pp, P1a, lacc1, gold, prev);
        } else {
            if (h == 0) trip4<4, false>(myF, BvA, TgA, pp, P4, lacc4, gold, prev);
            else        trip4<4, false>(myF, BvB, TgB, pp, P4, lacc4, gold, prev);
        }
    }

    // ---- store bounce through the same wave-private LDS region ----
    if (c == 0) {
        #pragma unroll
        for (int i = 0; i < 4; ++i) {
            const float p = P1a[i][0];                 // rank-1 lift
            stageW[(i << 6) + ((L + i) & 63)] = make_float4(p, p, p, p);
        }
        stageW[(4 << 6) + ((L + 4) & 63)] = make_float4(lacc1[0], lacc1[0], lacc1[0], lacc1[0]);
        stageW[(5 << 6) + ((L + 5) & 63)] = make_float4(gold, 0.f, 0.f, 0.f);
    } else {
        #pragma unroll
        for (int i = 0; i < 4; ++i)
            stageW[(i << 6) + ((L + i) & 63)] = make_float4(P4[i][0], P4[i][1], P4[i][2], P4[i][3]);
        stageW[(4 << 6) + ((L + 4) & 63)] = make_float4(lacc4[0], lacc4[1], lacc4[2], lacc4[3]);
        stageW[(5 << 6) + ((L + 5) & 63)] = make_float4(gold, 0.f, 0.f, 0.f);
    }
    // SLOT-major global layout (identical to round-1 / phase2), coalesced
    float4* gout = (float4*)matAll + ((size_t)b * 256 + (size_t)w * 64) * 6;
    #pragma unroll
    for (int r = 0; r < 6; ++r) {
        const int G  = r * 64 + L;
        const int cS = (G * 10923) >> 16;             // G/6
        const int q  = G - cS * 6;
        gout[G] = stageW[(q << 6) + ((cS + q) & 63)];
    }
}

// C = A∘B (A later, B earlier) in exp-space with per-column base-2 offsets.
__device__ __forceinline__ void compose4(
    const float (&Ae)[4][4], const float (&sa)[4],
    const float (&Be)[4][4], const float (&sb)[4],
    float (&Ce)[4][4], float (&sc)[4])
{
    const float maxA = fmaxf(fmaxf(sa[0], sa[1]), fmaxf(sa[2], sa[3]));
    float Ap[4][4];
    #pragma unroll
    for (int k = 0; k < 4; ++k) {
        const float wk = ex2(sa[k] - maxA);
        #pragma unroll
        for (int i = 0; i < 4; ++i) Ap[i][k] = Ae[i][k] * wk;
    }
    #pragma unroll
    for (int j = 0; j < 4; ++j) {
        float c0 = 0.f, c1 = 0.f, c2 = 0.f, c3 = 0.f;
        #pragma unroll
        for (int k = 0; k < 4; ++k) {
            const float bk = Be[k][j];
            c0 = fmaf(Ap[0][k], bk, c0);
            c1 = fmaf(Ap[1][k], bk, c1);
            c2 = fmaf(Ap[2][k], bk, c2);
            c3 = fmaf(Ap[3][k], bk, c3);
        }
        const float m = fmaxf(fmaxf(c0, c1), fmaxf(c2, c3));
        const int ee = (int)((__float_as_uint(m) >> 23) & 255u) - 126;
        const float scf = __uint_as_float((unsigned)(127 - ee) << 23);
        Ce[0][j] = c0 * scf; Ce[1][j] = c1 * scf;
        Ce[2][j] = c2 * scf; Ce[3][j] = c3 * scf;
        sc[j] = sb[j] + maxA + (float)ee;
    }
}

// phase2 (round-1 proven): lane holds CPL consecutive chunks, serial pre-compose,
// then in-wave ordered shuffle tree.
template <int CCv>
__global__ void __launch_bounds__(256)
crf_phase2(const float* __restrict__ matAll, const float* __restrict__ trans,
           const int* __restrict__ tags, float* __restrict__ out)
{
    constexpr int CPL = CCv / 64;
    const int gtid = blockIdx.x * 256 + threadIdx.x;
    const int b = gtid >> 6;
    const int lane = threadIdx.x & 63;

    const float4* base = (const float4*)(matAll + ((size_t)b * CCv + lane * CPL) * SLOT);
    float Pe[4][4], so[4], gold;
    {
        float A[SLOT];
        #pragma unroll
        for (int q = 0; q < SLOT / 4; ++q) {
            const float4 v = base[q];
            A[4*q] = v.x; A[4*q+1] = v.y; A[4*q+2] = v.z; A[4*q+3] = v.w;
        }
        #pragma unroll
        for (int i = 0; i < 4; ++i)
            #pragma unroll
            for (int j = 0; j < 4; ++j) Pe[i][j] = A[i * 4 + j];
        #pragma unroll
        for (int j = 0; j < 4; ++j) so[j] = A[16 + j];
        gold = A[20];
    }
    #pragma unroll
    for (int p = 1; p < CPL; ++p) {
        float A[SLOT];
        #pragma unroll
        for (int q = 0; q < SLOT / 4; ++q) {
            const float4 v = base[p * (SLOT / 4) + q];
            A[4*q] = v.x; A[4*q+1] = v.y; A[4*q+2] = v.z; A[4*q+3] = v.w;
        }
        float Ae[4][4], sa[4];
        #pragma unroll
        for (int i = 0; i < 4; ++i)
            #pragma unroll
            for (int j = 0; j < 4; ++j) Ae[i][j] = A[i * 4 + j];
        #pragma unroll
        for (int j = 0; j < 4; ++j) sa[j] = A[16 + j];
        gold += A[20];
        float Ce[4][4], sc[4];
        compose4(Ae, sa, Pe, so, Ce, sc);     // A is the later chunk
        #pragma unroll
        for (int i = 0; i < 4; ++i)
            #pragma unroll
            for (int j = 0; j < 4; ++j) Pe[i][j] = Ce[i][j];
        #pragma unroll
        for (int j = 0; j < 4; ++j) so[j] = sc[j];
    }

    #pragma unroll
    for (int d = 1; d < 64; d <<= 1) {
        float oP[4][4], os[4];
        #pragma unroll
        for (int i = 0; i < 4; ++i)
            #pragma unroll
            for (int j = 0; j < 4; ++j) oP[i][j] = __shfl_xor(Pe[i][j], d, 64);
        #pragma unroll
        for (int j = 0; j < 4; ++j) os[j] = __shfl_xor(so[j], d, 64);
        const bool hi = (lane & d) != 0;
        float Ae[4][4], Be[4][4], sa[4], sb[4];
        #pragma unroll
        for (int i = 0; i < 4; ++i)
            #pragma unroll
            for (int j = 0; j < 4; ++j) {
                Ae[i][j] = hi ? Pe[i][j] : oP[i][j];
                Be[i][j] = hi ? oP[i][j] : Pe[i][j];
            }
        #pragma unroll
        for (int j = 0; j < 4; ++j) {
            sa[j] = hi ? so[j] : os[j];
            sb[j] = hi ? os[j] : so[j];
        }
        float Ce[4][4], sc[4];
        compose4(Ae, sa, Be, sb, Ce, sc);
        #pragma unroll
        for (int i = 0; i < 4; ++i)
            #pragma unroll
            for (int j = 0; j < 4; ++j) Pe[i][j] = Ce[i][j];
        #pragma unroll
        for (int j = 0; j < 4; ++j) so[j] = sc[j];
    }

    #pragma unroll
    for (int d = 1; d < 64; d <<= 1) gold += __shfl_xor(gold, d, 64);

    if (lane == 0) {
        const float t50 = trans[30], t51 = trans[31], t52 = trans[32], t53 = trans[33];
        const float ssum = Pe[0][0] * ex2(t50 * kLog2e) + Pe[1][0] * ex2(t51 * kLog2e)
                         + Pe[2][0] * ex2(t52 * kLog2e) + Pe[3][0] * ex2(t53 * kLog2e);
        const float fwd = (so[0] + lg2(ssum)) * kLn2;
        const int lastT = tags[(size_t)b * TN + TN - 1];
        const float gfin = gold + sel4(t50, t51, t52, t53, lastT);
        out[b] = fwd - gfin;
    }
}

// ==================== fallback (round-1 kernels, small workspace) ====================
template <int NCOL, bool CHUNK0, int TCH>
__device__ __forceinline__ void run_chunk_fb(
    int b, int c,
    const float* __restrict__ feats, const float* __restrict__ bias,
    const int* __restrict__ tags, const P1Params& pp,
    float (&P)[4][NCOL], float (&lacc)[NCOL], float& gold, int& prev)
{
    const int t0c = c * TCH;
    #pragma unroll 1
    for (int bt = 0; bt < TCH / 8; ++bt) {
        const int t0 = t0c + bt * 8;
        float Fr[48];
        {
            const float4* fp4 = (const float4*)(feats + ((size_t)b * TN + t0) * 6);
            #pragma unroll
            for (int q = 0; q < 12; ++q) {
                const float4 vv = fp4[q];
                Fr[q*4+0] = vv.x; Fr[q*4+1] = vv.y; Fr[q*4+2] = vv.z; Fr[q*4+3] = vv.w;
            }
        }
        float Bv[8]; int Tg[8];
        {
            const float4* bp4 = (const float4*)(bias + (size_t)b * TN + t0);
            const float4 v0 = bp4[0], v1 = bp4[1];
            Bv[0]=v0.x; Bv[1]=v0.y; Bv[2]=v0.z; Bv[3]=v0.w;
            Bv[4]=v1.x; Bv[5]=v1.y; Bv[6]=v1.z; Bv[7]=v1.w;
            const int4* tp4 = (const int4*)(tags + (size_t)b * TN + t0);
            const int4 u0 = tp4[0], u1 = tp4[1];
            Tg[0]=u0.x; Tg[1]=u0.y; Tg[2]=u0.z; Tg[3]=u0.w;
            Tg[4]=u1.x; Tg[5]=u1.y; Tg[6]=u1.z; Tg[7]=u1.w;
        }
        #pragma unroll
        for (int s = 0; s < 8; ++s) {
            const float fi0 = Fr[s*6+0], fi1 = Fr[s*6+1];
            const float fi2 = Fr[s*6+2], fi3 = Fr[s*6+3];
            if (CHUNK0 && bt == 0 && s == 0) {
                const float a0 = fi0 + pp.tc4[0], a1 = fi1 + pp.tc4[1];
                const float a2 = fi2 + pp.tc4[2], a3 = fi3 + pp.tc4[3];
                const float mx = fmaxf(fmaxf(a0, a1), fmaxf(a2, a3));
                P[0][0] = ex2((a0 - mx) * kLog2e);
                P[1][0] = ex2((a1 - mx) * kLog2e);
                P[2][0] = ex2((a2 - mx) * kLog2e);
                P[3][0] = ex2((a3 - mx) * kLog2e);
                lacc[0] = mx * kLog2e;
                const int tg0 = Tg[0];
                gold = sel4(pp.tc4[0], pp.tc4[1], pp.tc4[2], pp.tc4[3], tg0)
                     + sel4(fi0, fi1, fi2, fi3, tg0);
                prev = tg0;
                continue;
            }
            step_generic<NCOL>(pp, fi0, fi1, fi2, fi3, Bv[s], Tg[s],
                               (s & 3) == 3, P, lacc, gold, prev);
        }
    }
}

template <int CCv>
__global__ void __launch_bounds__(256)
crf_phase1_fb(const float* __restrict__ feats, const float* __restrict__ bias,
              const int* __restrict__ tags, const float* __restrict__ trans,
              const float* __restrict__ wsh, const float* __restrict__ bno,
              const float* __restrict__ bwi, const float* __restrict__ wwo,
              const float* __restrict__ wno, const float* __restrict__ mult,
              float* __restrict__ matAll)
{
    constexpr int TCHv = TN / CCv;
    constexpr int BPB  = 256 / CCv;
    const int b = blockIdx.x * BPB + (threadIdx.x / CCv);
    const int c = threadIdx.x % CCv;

    __shared__ float sA[16], sM[16];
    if (threadIdx.x < 16) {
        const int i = threadIdx.x >> 2, j = threadIdx.x & 3;
        sA[threadIdx.x] = trans[i * 6 + j];
        const float m0 = mult[j], m1 = mult[4 + j], m2 = mult[8 + j], m3 = mult[12 + j];
        const float mx = fmaxf(fmaxf(m0, m1), fmaxf(m2, m3));
        const float e0 = ex2((m0 - mx) * kLog2e), e1 = ex2((m1 - mx) * kLog2e);
        const float e2 = ex2((m2 - mx) * kLog2e), e3 = ex2((m3 - mx) * kLog2e);
        const float inv = rcpf(e0 + e1 + e2 + e3);
        const float ei = (i == 0) ? e0 : (i == 1) ? e1 : (i == 2) ? e2 : e3;
        sM[threadIdx.x] = (i == j) ? -1.0f : ei * inv;
    }
    __syncthreads();

    P1Params pp;
    #pragma unroll
    for (int i = 0; i < 4; ++i)
        #pragma unroll
        for (int j = 0; j < 4; ++j) {
            pp.AL[i][j] = trans[i * 6 + j] * kLog2e;
            pp.M[i][j]  = sM[i * 4 + j];
        }
    #pragma unroll
    for (int j = 0; j < 4; ++j) { pp.wsv[j] = wsh[j]; pp.wwv[j] = wwo[j]; pp.wnv[j] = wno[j]; }
    pp.bwc = bwi[0]; pp.bnc = bno[0];
    pp.sA = sA; pp.sM = sM;
    pp.tc4[0] = trans[4]; pp.tc4[1] = trans[10]; pp.tc4[2] = trans[16]; pp.tc4[3] = trans[22];

    float o[SLOT];
    float gold = 0.0f;
    int prev;
    if (c == 0) {
        float P[4][1], lacc[1];
        run_chunk_fb<1, true, TCHv>(b, 0, feats, bias, tags, pp, P, lacc, gold, prev);
        #pragma unroll
        for (int i = 0; i < 4; ++i)
            #pragma unroll
            for (int j = 0; j < 4; ++j) o[i * 4 + j] = P[i][0];
        #pragma unroll
        for (int j = 0; j < 4; ++j) o[16 + j] = lacc[0];
    } else {
        float P[4][4], lacc[4] = {0.f, 0.f, 0.f, 0.f};
        #pragma unroll
        for (int i = 0; i < 4; ++i)
            #pragma unroll
            for (int j = 0; j < 4; ++j) P[i][j] = (i == j) ? 1.0f : 0.0f;
        prev = tags[(size_t)b * TN + c * TCHv - 1];
        run_chunk_fb<4, false, TCHv>(b, c, feats, bias, tags, pp, P, lacc, gold, prev);
        #pragma unroll
        for (int i = 0; i < 4; ++i)
            #pragma unroll
            for (int j = 0; j < 4; ++j) o[i * 4 + j] = P[i][j];
        #pragma unroll
        for (int j = 0; j < 4; ++j) o[16 + j] = lacc[j];
    }
    o[20] = gold; o[21] = 0.f; o[22] = 0.f; o[23] = 0.f;
    float4* s4 = (float4*)(matAll + ((size_t)b * CCv + c) * SLOT);
    #pragma unroll
    for (int q = 0; q < SLOT / 4; ++q)
        s4[q] = make_float4(o[4*q], o[4*q+1], o[4*q+2], o[4*q+3]);
}

extern "C" void kernel_launch(void* const* d_in, const int* in_sizes, int n_in,
                              void* d_out, int out_size, void* d_ws, size_t ws_size,
                              hipStream_t stream)
{
    const float* feats = (const float*)d_in[0];
    const float* bias  = (const float*)d_in[1];
    const int*   tags  = (const int*)d_in[2];
    const float* trans = (const float*)d_in[3];
    const float* wsh   = (const float*)d_in[4];
    const float* bno   = (const float*)d_in[5];
    const float* bwi   = (const float*)d_in[6];
    const float* wwo   = (const float*)d_in[7];
    const float* wno   = (const float*)d_in[8];
    const float* mult  = (const float*)d_in[9];
    float* out = (float*)d_out;
    float* matAll = (float*)d_ws;

    const size_t need256 = (size_t)BN * 256 * SLOT * sizeof(float);  // 50.3 MB
    const size_t need128 = (size_t)BN * 128 * SLOT * sizeof(float);  // 25.2 MB
    if (ws_size >= need256) {
        crf_phase1_t<<<BN, 256, 0, stream>>>(
            feats, bias, tags, trans, wsh, bno, bwi, wwo, wno, mult, matAll);
        crf_phase2<256><<<(BN * 64) / 256, 256, 0, stream>>>(matAll, trans, tags, out);
    } else if (ws_size >= need128) {
        crf_phase1_fb<128><<<(128 * BN) / 256, 256, 0, stream>>>(
            feats, bias, tags, trans, wsh, bno, bwi, wwo, wno, mult, matAll);
        crf_phase2<128><<<(BN * 64) / 256, 256, 0, stream>>>(matAll, trans, tags, out);
    } else {
        crf_phase1_fb<64><<<(64 * BN) / 256, 256, 0, stream>>>(
            feats, bias, tags, trans, wsh, bno, bwi, wwo, wno, mult, matAll);
        crf_phase2<64><<<(BN * 64) / 256, 256, 0, stream>>>(matAll, trans, tags, out);
    }
}